// Round 9
// baseline (368.155 us; speedup 1.0000x reference)
//
#include <hip/hip_runtime.h>
#include <hip/hip_fp16.h>
#include <math.h>

#define NN 20000
#define NE 320000
#define NB 128
#define SLOPE 0.2f
#define BN_EPS 1e-5f
#define NBLK 79   // ceil(NN/256)

__device__ __forceinline__ unsigned short f2bf(float f) {
    unsigned int u = __float_as_uint(f);
    unsigned int r = (u + 0x7FFFu + ((u >> 16) & 1u)) >> 16;
    return (unsigned short)r;
}
__device__ __forceinline__ float bf2f(unsigned short h) {
    return __uint_as_float(((unsigned int)h) << 16);
}

// ---------- CSR build ----------
__global__ __launch_bounds__(256) void k_hist(const int* __restrict__ dst, int* __restrict__ deg) {
    int e = blockIdx.x * 256 + threadIdx.x;
    if (e < NE) atomicAdd(&deg[dst[e]], 1);
}

__global__ __launch_bounds__(256) void k_scanA(const int* __restrict__ deg, int* __restrict__ bsum) {
    __shared__ int wsum[4];
    int t = threadIdx.x;
    int idx = blockIdx.x * 256 + t;
    int v = (idx < NN) ? deg[idx] : 0;
    for (int off = 32; off > 0; off >>= 1) v += __shfl_xor(v, off);
    if ((t & 63) == 0) wsum[t >> 6] = v;
    __syncthreads();
    if (t == 0) bsum[blockIdx.x] = wsum[0] + wsum[1] + wsum[2] + wsum[3];
}

__global__ __launch_bounds__(64) void k_scanB(const int* __restrict__ bsum, int* __restrict__ boff,
                                              int* __restrict__ rowptr) {
    int l = threadIdx.x;
    int v0 = (l < NBLK) ? bsum[l] : 0;
    int v1 = (64 + l < NBLK) ? bsum[64 + l] : 0;
    int o0 = v0, o1 = v1;
    for (int off = 1; off < 64; off <<= 1) { int u = __shfl_up(v0, off); if (l >= off) v0 += u; }
    int tot0 = __shfl(v0, 63);
    for (int off = 1; off < 64; off <<= 1) { int u = __shfl_up(v1, off); if (l >= off) v1 += u; }
    int tot1 = __shfl(v1, 63);
    if (l < NBLK) boff[l] = v0 - o0;
    if (64 + l < NBLK) boff[64 + l] = tot0 + v1 - o1;
    if (l == 0) rowptr[NN] = tot0 + tot1;
}

__global__ __launch_bounds__(256) void k_scanC(const int* __restrict__ deg, const int* __restrict__ boff,
                                               int* __restrict__ rowptr, int* __restrict__ cursor) {
    __shared__ int wsum[4];
    int t = threadIdx.x, lane = t & 63, w = t >> 6;
    int idx = blockIdx.x * 256 + t;
    int v = (idx < NN) ? deg[idx] : 0;
    int incl = v;
    for (int off = 1; off < 64; off <<= 1) { int u = __shfl_up(incl, off); if (lane >= off) incl += u; }
    if (lane == 63) wsum[w] = incl;
    __syncthreads();
    int pre = 0;
    for (int i = 0; i < w; ++i) pre += wsum[i];
    int excl = incl - v + pre + boff[blockIdx.x];
    if (idx < NN) { rowptr[idx] = excl; cursor[idx] = excl; }
}

// ---------- precompute: ve (edge-dot vectors) + w2e, both layers ----------
__global__ __launch_bounds__(256) void k_p1(const float* __restrict__ We, const float* __restrict__ atte,
                                            float* __restrict__ ve01, float* __restrict__ w2e01) {
    int L = blockIdx.x;
    const float* WeL = We + (size_t)L * 128 * 128;
    const float* aeL = atte + L * 128;
    int t = threadIdx.x;
    int h = (t >> 6) & 1;
    int k = t & 63;
    int row = (t < 128) ? k : (64 + k);
    float acc = 0.f;
    for (int c = 0; c < 64; ++c) acc += WeL[row * 128 + h * 64 + c] * aeL[h * 64 + c];
    if (t < 128) ve01[L * 128 + t] = acc;
    else        w2e01[L * 128 + (t - 128)] = acc;
}

// ---------- insl + ce for BOTH layers in one dispatch ----------
__global__ __launch_bounds__(256) void k_p2both(const float* __restrict__ instr, const float* __restrict__ Wl,
                                                const float* __restrict__ w2e01,
                                                float* __restrict__ insl01, float* __restrict__ ce01) {
    int blk = blockIdx.x, t = threadIdx.x;
    if (blk < 128) {
        int L = blk >> 6;
        int idx = (blk & 63) * 256 + t;
        int b = idx >> 7, j = idx & 127;
        const float* ins = instr + (size_t)L * NB * 64;
        const float* WlL = Wl + (size_t)L * 128 * 128;
        float acc = 0.f;
        for (int k = 0; k < 64; ++k) acc += ins[b * 64 + k] * WlL[(64 + k) * 128 + j];
        insl01[(size_t)L * 16384 + idx] = acc;
    } else {
        int L = blk - 128;
        int b = t >> 1, h = t & 1;
        const float* ins = instr + (size_t)L * NB * 64;
        const float* w2 = w2e01 + L * 128 + h * 64;
        float acc = 0.f;
        for (int k = 0; k < 64; ++k) acc += ins[b * 64 + k] * w2[k];
        ce01[L * 256 + b * 2 + h] = acc;
    }
}

// ---------- node linear: xl (bf16) + alc (= al + ce[batch]) + ar; optional fused BN+relu ----------
__global__ __launch_bounds__(256) void k_node(const float* __restrict__ hcur, const float* __restrict__ Wl,
                                              const float* __restrict__ insl, const int* __restrict__ batch,
                                              const float* __restrict__ attl, const float* __restrict__ attr_,
                                              const float2* __restrict__ ce2,
                                              const float* __restrict__ scsh, int use_bn,
                                              unsigned short* __restrict__ xlh,
                                              float* __restrict__ alc, float* __restrict__ ar) {
    __shared__ float sh[8 * 64];
    int t = threadIdx.x;
    int row0 = blockIdx.x * 8;
    for (int idx = t; idx < 512; idx += 256) {
        int r = idx >> 6, k = idx & 63;
        int n = row0 + r;
        float hv = (n < NN) ? hcur[n * 64 + k] : 0.f;
        if (use_bn) hv = fmaxf(hv * scsh[k] + scsh[64 + k], 0.f);
        sh[idx] = hv;
    }
    __syncthreads();
    int w = t >> 6, lane = t & 63;
    int h = w & 1;
    int rbase = (w >> 1) * 4;
    int j = h * 64 + lane;
    float attlv = attl[j];
    float attrv = attr_[j];
    float acc0 = 0.f, acc1 = 0.f, acc2 = 0.f, acc3 = 0.f;
    for (int k = 0; k < 64; ++k) {
        float wv = Wl[k * 128 + j];
        acc0 += sh[(rbase + 0) * 64 + k] * wv;
        acc1 += sh[(rbase + 1) * 64 + k] * wv;
        acc2 += sh[(rbase + 2) * 64 + k] * wv;
        acc3 += sh[(rbase + 3) * 64 + k] * wv;
    }
    float accs[4] = {acc0, acc1, acc2, acc3};
    for (int rr = 0; rr < 4; ++rr) {
        int n = row0 + rbase + rr;
        if (n >= NN) break;
        int b = batch[n];
        float v = accs[rr] + insl[b * 128 + j];
        xlh[(size_t)n * 128 + j] = f2bf(v);
        float pl = v * attlv, pr = v * attrv;
        for (int off = 32; off > 0; off >>= 1) {
            pl += __shfl_xor(pl, off);
            pr += __shfl_xor(pr, off);
        }
        if (lane == 0) {
            float2 cb = ce2[b];
            alc[n * 2 + h] = pl + (h ? cb.y : cb.x);
            ar[n * 2 + h] = pr;
        }
    }
}

// ---------- lane-dense edge dots (both layers) -> one 16B CSR-order record ----------
// Each thread owns 4 edges; zero shuffles, zero divergence; dots stored fp16.
__global__ __launch_bounds__(256) void k_sced(const int* __restrict__ src, const int* __restrict__ dst,
                                              const float* __restrict__ eattr, const float* __restrict__ ve01,
                                              int* __restrict__ cursor, int4* __restrict__ rec) {
    __shared__ float sv[256];
    int t = threadIdx.x;
    sv[t] = ve01[t];
    __syncthreads();
    const float4* sv4 = (const float4*)sv;
#pragma unroll
    for (int j = 0; j < 4; ++j) {
        int e = blockIdx.x * 1024 + j * 256 + t;
        if (e >= NE) return;
        const float4* row = (const float4*)(eattr + (size_t)e * 64);
        float d0 = 0.f, d1 = 0.f, d2 = 0.f, d3 = 0.f;
#pragma unroll 4
        for (int q = 0; q < 16; ++q) {
            float4 f = row[q];
            float4 u0 = sv4[q], u1 = sv4[16 + q], u2 = sv4[32 + q], u3 = sv4[48 + q];
            d0 += f.x * u0.x + f.y * u0.y + f.z * u0.z + f.w * u0.w;
            d1 += f.x * u1.x + f.y * u1.y + f.z * u1.z + f.w * u1.w;
            d2 += f.x * u2.x + f.y * u2.y + f.z * u2.z + f.w * u2.w;
            d3 += f.x * u3.x + f.y * u3.y + f.z * u3.z + f.w * u3.w;
        }
        int s = src[e], dd = dst[e];
        int pos = atomicAdd(&cursor[dd], 1);
        __half2 h01 = __floats2half2_rn(d0, d1);
        __half2 h23 = __floats2half2_rn(d2, d3);
        rec[pos] = make_int4(s, *(int*)&h01, *(int*)&h23, 0);
    }
}

// ---------- gather: logits+exp inline; 1 wave/node; ssum in-wave; optional BN on residual ----------
__global__ __launch_bounds__(256) void k_gather(const int* __restrict__ rowptr, const int4* __restrict__ rec,
                                                const unsigned int* __restrict__ xl32,
                                                const float2* __restrict__ alc2, const float2* __restrict__ ar2,
                                                const float* __restrict__ bias, const float* __restrict__ hprev,
                                                const float* __restrict__ scsh, int use_bn, int layer,
                                                float* __restrict__ hnew) {
    int t = threadIdx.x;
    int w = t >> 6, lane = t & 63;
    int n = blockIdx.x * 4 + w;
    if (n >= NN) return;
    int r0 = rowptr[n], r1 = rowptr[n + 1];
    float2 arn = ar2[n];
    float acc0 = 0.f, acc1 = 0.f, ss = 0.f;
    const unsigned int* xlp = xl32 + lane;
#pragma unroll 8
    for (int p = r0; p < r1; ++p) {
        int4 r = rec[p];                         // 16B wave-uniform sequential load
        int s = r.x;
        int dw = layer ? r.z : r.y;
        __half2 hh = *(__half2*)&dw;
        float2 d = __half22float2(hh);
        float2 al = alc2[s];                     // wave-uniform broadcast gather (L2-hot)
        float a0 = al.x + arn.x + d.x;
        float a1 = al.y + arn.y + d.y;
        a0 = (a0 > 0.f) ? a0 : SLOPE * a0;
        a1 = (a1 > 0.f) ? a1 : SLOPE * a1;
        float ex = (lane < 32) ? __expf(a0) : __expf(a1);
        unsigned int pr = xlp[(size_t)s * 64];   // coalesced 256B/wave gather
        ss += ex;
        acc0 += ex * bf2f((unsigned short)(pr & 0xFFFFu));
        acc1 += ex * bf2f((unsigned short)(pr >> 16));
    }
    float inv_s = 1.f / (ss + 1e-16f);
    acc0 *= inv_s; acc1 *= inv_s;
    float o0 = 0.5f * (acc0 + __shfl_xor(acc0, 32));
    float o1 = 0.5f * (acc1 + __shfl_xor(acc1, 32));
    if (lane < 32) {
        float2 hv = ((const float2*)(hprev + (size_t)n * 64))[lane];
        if (use_bn) {
            float2 sc = ((const float2*)scsh)[lane];
            float2 sf = ((const float2*)(scsh + 64))[lane];
            hv.x = fmaxf(hv.x * sc.x + sf.x, 0.f);
            hv.y = fmaxf(hv.y * sc.y + sf.y, 0.f);
        }
        float2 bv = ((const float2*)bias)[lane];
        float2 o;
        o.x = o0 + bv.x + hv.x;
        o.y = o1 + bv.y + hv.y;
        ((float2*)(hnew + (size_t)n * 64))[lane] = o;
    }
}

// ---------- BN stats on pre-BN hbuf ----------
__global__ __launch_bounds__(256) void k_bnstat(const float* __restrict__ hbuf,
                                                float* __restrict__ part, float* __restrict__ partsq) {
    __shared__ float sA[256], sB[256];
    int t = threadIdx.x;
    int c = t & 63, r = t >> 6;
    int n0 = blockIdx.x * 80;
    float s = 0.f, s2 = 0.f;
    for (int i = 0; i < 20; ++i) {
        float v = hbuf[(size_t)(n0 + i * 4 + r) * 64 + c];
        s += v; s2 += v * v;
    }
    sA[t] = s; sB[t] = s2;
    __syncthreads();
    if (t < 64) {
        part[blockIdx.x * 64 + t]   = sA[t] + sA[t + 64] + sA[t + 128] + sA[t + 192];
        partsq[blockIdx.x * 64 + t] = sB[t] + sB[t + 64] + sB[t + 128] + sB[t + 192];
    }
}

__global__ __launch_bounds__(256) void k_bnred(const float* __restrict__ part, const float* __restrict__ partsq,
                                               const float* __restrict__ gamma, const float* __restrict__ beta,
                                               float* __restrict__ scsh) {
    __shared__ float sA[256], sB[256];
    int t = threadIdx.x;
    int c = t & 63, q = t >> 6;
    float s = 0.f, s2 = 0.f;
    for (int j = q; j < 250; j += 4) { s += part[j * 64 + c]; s2 += partsq[j * 64 + c]; }
    sA[t] = s; sB[t] = s2;
    __syncthreads();
    if (t < 64) {
        float su = sA[t] + sA[t + 64] + sA[t + 128] + sA[t + 192];
        float sq = sB[t] + sB[t + 64] + sB[t + 128] + sB[t + 192];
        float mu = su * (1.f / NN);
        float var = sq * (1.f / NN) - mu * mu;
        float sc = gamma[t] * rsqrtf(var + BN_EPS);
        scsh[t] = sc;
        scsh[64 + t] = beta[t] - mu * sc;
    }
}

extern "C" void kernel_launch(void* const* d_in, const int* in_sizes, int n_in,
                              void* d_out, int out_size, void* d_ws, size_t ws_size,
                              hipStream_t stream) {
    (void)in_sizes; (void)n_in; (void)out_size; (void)ws_size;
    const float* x     = (const float*)d_in[0];
    const int*   eidx  = (const int*)d_in[1];
    const float* eattr = (const float*)d_in[2];
    const float* instr = (const float*)d_in[3];
    const int*   batch = (const int*)d_in[4];
    const float* W_l   = (const float*)d_in[5];
    const float* W_e   = (const float*)d_in[6];
    const float* att_l = (const float*)d_in[7];
    const float* att_r = (const float*)d_in[8];
    const float* att_e = (const float*)d_in[9];
    const float* bias  = (const float*)d_in[10];
    const float* bn_g  = (const float*)d_in[11];
    const float* bn_b  = (const float*)d_in[12];
    float* out = (float*)d_out;

    const int* src = eidx;
    const int* dst = eidx + NE;

    char* ws = (char*)d_ws;
    int4*   rec     = (int4*)ws;       ws += (size_t)NE * 16;
    unsigned short* xlh = (unsigned short*)ws; ws += (size_t)NN * 128 * 2;
    int*    deg     = (int*)ws;        ws += NN * 4;
    int*    rowptr  = (int*)ws;        ws += (NN + 1) * 4 + 4;
    int*    cursor  = (int*)ws;        ws += NN * 4;
    int*    bsum    = (int*)ws;        ws += 80 * 4;
    int*    boff    = (int*)ws;        ws += 80 * 4;
    float*  alc     = (float*)ws;      ws += NN * 2 * 4;
    float*  ar      = (float*)ws;      ws += NN * 2 * 4;
    float*  insl01  = (float*)ws;      ws += 2 * 128 * 128 * 4;
    float*  ve01    = (float*)ws;      ws += 256 * 4;
    float*  w2e01   = (float*)ws;      ws += 256 * 4;
    float*  ce01    = (float*)ws;      ws += 2 * 256 * 4;
    float*  hbuf    = (float*)ws;      ws += (size_t)NN * 64 * 4;
    float*  part    = (float*)ws;      ws += 250 * 64 * 4;
    float*  partsq  = (float*)ws;      ws += 250 * 64 * 4;
    float*  scsh    = (float*)ws;      ws += 128 * 4;

    hipMemsetAsync(deg, 0, NN * 4, stream);
    k_hist<<<(NE + 255) / 256, 256, 0, stream>>>(dst, deg);
    k_scanA<<<NBLK, 256, 0, stream>>>(deg, bsum);
    k_scanB<<<1, 64, 0, stream>>>(bsum, boff, rowptr);
    k_scanC<<<NBLK, 256, 0, stream>>>(deg, boff, rowptr, cursor);

    k_p1<<<2, 256, 0, stream>>>(W_e, att_e, ve01, w2e01);
    k_p2both<<<130, 256, 0, stream>>>(instr, W_l, w2e01, insl01, ce01);

    // edge dots for both layers, CSR order (independent of node features)
    k_sced<<<(NE + 1023) / 1024, 256, 0, stream>>>(src, dst, eattr, ve01, cursor, rec);

    // layer 0
    k_node<<<(NN + 7) / 8, 256, 0, stream>>>(x, W_l, insl01, batch,
                                             att_l, att_r, (const float2*)ce01,
                                             scsh, 0, xlh, alc, ar);
    k_gather<<<NN / 4, 256, 0, stream>>>(rowptr, rec, (const unsigned int*)xlh,
                                         (const float2*)alc, (const float2*)ar,
                                         bias, x, scsh, 0, 0, hbuf);
    k_bnstat<<<250, 256, 0, stream>>>(hbuf, part, partsq);
    k_bnred<<<1, 256, 0, stream>>>(part, partsq, bn_g, bn_b, scsh);

    // layer 1
    k_node<<<(NN + 7) / 8, 256, 0, stream>>>(hbuf, W_l + 128 * 128, insl01 + 16384, batch,
                                             att_l + 128, att_r + 128, (const float2*)(ce01 + 256),
                                             scsh, 1, xlh, alc, ar);
    k_gather<<<NN / 4, 256, 0, stream>>>(rowptr, rec, (const unsigned int*)xlh,
                                         (const float2*)alc, (const float2*)ar,
                                         bias + 64, hbuf, scsh, 1, 1, out);
}

// Round 10
// 296.932 us; speedup vs baseline: 1.2399x; 1.2399x over previous
//
#include <hip/hip_runtime.h>
#include <hip/hip_fp16.h>
#include <math.h>

#define NN 20000
#define NE 320000
#define NB 128
#define SLOPE 0.2f
#define BN_EPS 1e-5f
#define NBLK 79   // ceil(NN/256)
#define ROWS 65   // LDS row stride (bank-conflict-free padding)

__device__ __forceinline__ unsigned short f2bf(float f) {
    unsigned int u = __float_as_uint(f);
    unsigned int r = (u + 0x7FFFu + ((u >> 16) & 1u)) >> 16;
    return (unsigned short)r;
}
__device__ __forceinline__ float bf2f(unsigned short h) {
    return __uint_as_float(((unsigned int)h) << 16);
}

// ---------- CSR build ----------
__global__ __launch_bounds__(256) void k_hist(const int* __restrict__ dst, int* __restrict__ deg) {
    int e = blockIdx.x * 256 + threadIdx.x;
    if (e < NE) atomicAdd(&deg[dst[e]], 1);
}

__global__ __launch_bounds__(256) void k_scanA(const int* __restrict__ deg, int* __restrict__ bsum) {
    __shared__ int wsum[4];
    int t = threadIdx.x;
    int idx = blockIdx.x * 256 + t;
    int v = (idx < NN) ? deg[idx] : 0;
    for (int off = 32; off > 0; off >>= 1) v += __shfl_xor(v, off);
    if ((t & 63) == 0) wsum[t >> 6] = v;
    __syncthreads();
    if (t == 0) bsum[blockIdx.x] = wsum[0] + wsum[1] + wsum[2] + wsum[3];
}

__global__ __launch_bounds__(64) void k_scanB(const int* __restrict__ bsum, int* __restrict__ boff,
                                              int* __restrict__ rowptr) {
    int l = threadIdx.x;
    int v0 = (l < NBLK) ? bsum[l] : 0;
    int v1 = (64 + l < NBLK) ? bsum[64 + l] : 0;
    int o0 = v0, o1 = v1;
    for (int off = 1; off < 64; off <<= 1) { int u = __shfl_up(v0, off); if (l >= off) v0 += u; }
    int tot0 = __shfl(v0, 63);
    for (int off = 1; off < 64; off <<= 1) { int u = __shfl_up(v1, off); if (l >= off) v1 += u; }
    int tot1 = __shfl(v1, 63);
    if (l < NBLK) boff[l] = v0 - o0;
    if (64 + l < NBLK) boff[64 + l] = tot0 + v1 - o1;
    if (l == 0) rowptr[NN] = tot0 + tot1;
}

__global__ __launch_bounds__(256) void k_scanC(const int* __restrict__ deg, const int* __restrict__ boff,
                                               int* __restrict__ rowptr, int* __restrict__ cursor) {
    __shared__ int wsum[4];
    int t = threadIdx.x, lane = t & 63, w = t >> 6;
    int idx = blockIdx.x * 256 + t;
    int v = (idx < NN) ? deg[idx] : 0;
    int incl = v;
    for (int off = 1; off < 64; off <<= 1) { int u = __shfl_up(incl, off); if (lane >= off) incl += u; }
    if (lane == 63) wsum[w] = incl;
    __syncthreads();
    int pre = 0;
    for (int i = 0; i < w; ++i) pre += wsum[i];
    int excl = incl - v + pre + boff[blockIdx.x];
    if (idx < NN) { rowptr[idx] = excl; cursor[idx] = excl; }
}

// ---------- precompute: ve (edge-dot vectors) + w2e, both layers ----------
__global__ __launch_bounds__(256) void k_p1(const float* __restrict__ We, const float* __restrict__ atte,
                                            float* __restrict__ ve01, float* __restrict__ w2e01) {
    int L = blockIdx.x;
    const float* WeL = We + (size_t)L * 128 * 128;
    const float* aeL = atte + L * 128;
    int t = threadIdx.x;
    int h = (t >> 6) & 1;
    int k = t & 63;
    int row = (t < 128) ? k : (64 + k);
    float acc = 0.f;
    for (int c = 0; c < 64; ++c) acc += WeL[row * 128 + h * 64 + c] * aeL[h * 64 + c];
    if (t < 128) ve01[L * 128 + t] = acc;
    else        w2e01[L * 128 + (t - 128)] = acc;
}

// ---------- insl + ce for BOTH layers in one dispatch ----------
__global__ __launch_bounds__(256) void k_p2both(const float* __restrict__ instr, const float* __restrict__ Wl,
                                                const float* __restrict__ w2e01,
                                                float* __restrict__ insl01, float* __restrict__ ce01) {
    int blk = blockIdx.x, t = threadIdx.x;
    if (blk < 128) {
        int L = blk >> 6;
        int idx = (blk & 63) * 256 + t;
        int b = idx >> 7, j = idx & 127;
        const float* ins = instr + (size_t)L * NB * 64;
        const float* WlL = Wl + (size_t)L * 128 * 128;
        float acc = 0.f;
        for (int k = 0; k < 64; ++k) acc += ins[b * 64 + k] * WlL[(64 + k) * 128 + j];
        insl01[(size_t)L * 16384 + idx] = acc;
    } else {
        int L = blk - 128;
        int b = t >> 1, h = t & 1;
        const float* ins = instr + (size_t)L * NB * 64;
        const float* w2 = w2e01 + L * 128 + h * 64;
        float acc = 0.f;
        for (int k = 0; k < 64; ++k) acc += ins[b * 64 + k] * w2[k];
        ce01[L * 256 + b * 2 + h] = acc;
    }
}

// ---------- node linear: xl (bf16) + alc (= al + ce[batch]) + ar; optional fused BN+relu ----------
__global__ __launch_bounds__(256) void k_node(const float* __restrict__ hcur, const float* __restrict__ Wl,
                                              const float* __restrict__ insl, const int* __restrict__ batch,
                                              const float* __restrict__ attl, const float* __restrict__ attr_,
                                              const float2* __restrict__ ce2,
                                              const float* __restrict__ scsh, int use_bn,
                                              unsigned short* __restrict__ xlh,
                                              float* __restrict__ alc, float* __restrict__ ar) {
    __shared__ float sh[8 * 64];
    int t = threadIdx.x;
    int row0 = blockIdx.x * 8;
    for (int idx = t; idx < 512; idx += 256) {
        int r = idx >> 6, k = idx & 63;
        int n = row0 + r;
        float hv = (n < NN) ? hcur[n * 64 + k] : 0.f;
        if (use_bn) hv = fmaxf(hv * scsh[k] + scsh[64 + k], 0.f);
        sh[idx] = hv;
    }
    __syncthreads();
    int w = t >> 6, lane = t & 63;
    int h = w & 1;
    int rbase = (w >> 1) * 4;
    int j = h * 64 + lane;
    float attlv = attl[j];
    float attrv = attr_[j];
    float acc0 = 0.f, acc1 = 0.f, acc2 = 0.f, acc3 = 0.f;
    for (int k = 0; k < 64; ++k) {
        float wv = Wl[k * 128 + j];
        acc0 += sh[(rbase + 0) * 64 + k] * wv;
        acc1 += sh[(rbase + 1) * 64 + k] * wv;
        acc2 += sh[(rbase + 2) * 64 + k] * wv;
        acc3 += sh[(rbase + 3) * 64 + k] * wv;
    }
    float accs[4] = {acc0, acc1, acc2, acc3};
    for (int rr = 0; rr < 4; ++rr) {
        int n = row0 + rbase + rr;
        if (n >= NN) break;
        int b = batch[n];
        float v = accs[rr] + insl[b * 128 + j];
        xlh[(size_t)n * 128 + j] = f2bf(v);
        float pl = v * attlv, pr = v * attrv;
        for (int off = 32; off > 0; off >>= 1) {
            pl += __shfl_xor(pl, off);
            pr += __shfl_xor(pr, off);
        }
        if (lane == 0) {
            float2 cb = ce2[b];
            alc[n * 2 + h] = pl + (h ? cb.y : cb.x);
            ar[n * 2 + h] = pr;
        }
    }
}

// ---------- edge kernel v3: 1 wave/block, 64 edges; LDS transpose; lane-dense dots ----------
// Fuses layer-0 logits+exp. One 16B CSR-slot record: {s|(d<<15), half2(d2,d3), s, half2(ex0,ex1)}.
__global__ __launch_bounds__(64) void k_sced(const int* __restrict__ src, const int* __restrict__ dst,
                                             const float* __restrict__ eattr, const float* __restrict__ ve01,
                                             const float2* __restrict__ alc2, const float2* __restrict__ ar2,
                                             int* __restrict__ cursor, int4* __restrict__ einfo) {
    __shared__ float se[64 * ROWS];
    __shared__ float svT[256];
    int lane = threadIdx.x;
    // transpose ve01 -> svT[4k+j] = ve01[j*64+k]  (single wave; no barrier needed)
#pragma unroll
    for (int i = 0; i < 4; ++i) {
        int idx = i * 64 + lane;
        svT[idx] = ve01[(idx & 3) * 64 + (idx >> 2)];
    }
    int ebase = blockIdx.x * 64;
    // stage 64 edges x 64 floats, fully coalesced (1KB per wave-instruction)
    const float4* gsrc = (const float4*)eattr + (size_t)ebase * 16;
#pragma unroll
    for (int i = 0; i < 16; ++i) {
        int fi = i * 64 + lane;          // float4 index within the 64-edge tile
        float4 f = gsrc[fi];
        int el = fi >> 4, q = fi & 15;
        float* dp = se + el * ROWS + q * 4;
        dp[0] = f.x; dp[1] = f.y; dp[2] = f.z; dp[3] = f.w;
    }
    // lane-dense: lane owns edge ebase+lane. Row reads 2-way bank-aliased (free), svT b128 broadcast.
    const float* row = se + lane * ROWS;
    float d0 = 0.f, d1 = 0.f, d2 = 0.f, d3 = 0.f;
#pragma unroll
    for (int k = 0; k < 64; ++k) {
        float fv = row[k];
        float4 vt = *(const float4*)&svT[4 * k];
        d0 += fv * vt.x; d1 += fv * vt.y; d2 += fv * vt.z; d3 += fv * vt.w;
    }
    int e = ebase + lane;
    int s = src[e], dd = dst[e];
    float2 al = alc2[s], arr = ar2[dd];
    float a0 = al.x + arr.x + d0;
    float a1 = al.y + arr.y + d1;
    a0 = (a0 > 0.f) ? a0 : SLOPE * a0;
    a1 = (a1 > 0.f) ? a1 : SLOPE * a1;
    __half2 ex = __floats2half2_rn(__expf(a0), __expf(a1));
    __half2 d23 = __floats2half2_rn(d2, d3);
    int pos = atomicAdd(&cursor[dd], 1);
    einfo[pos] = make_int4(s | (dd << 15), *(int*)&d23, s, *(int*)&ex);
}

// ---------- layer-1 logits + exp (CSR order, coalesced read/write) ----------
__global__ __launch_bounds__(256) void k_attnexp(const int4* __restrict__ einfo,
                                                 const float2* __restrict__ alc2, const float2* __restrict__ ar2,
                                                 int2* __restrict__ rec1) {
    int p = blockIdx.x * 256 + threadIdx.x;
    if (p >= NE) return;
    int4 r = einfo[p];
    int s = r.x & 0x7FFF, d = r.x >> 15;
    __half2 hd = *(__half2*)&r.y;
    float2 dv = __half22float2(hd);
    float2 a_l = alc2[s];
    float2 a_r = ar2[d];
    float a0 = a_l.x + a_r.x + dv.x;
    float a1 = a_l.y + a_r.y + dv.y;
    a0 = (a0 > 0.f) ? a0 : SLOPE * a0;
    a1 = (a1 > 0.f) ? a1 : SLOPE * a1;
    __half2 hx = __floats2half2_rn(__expf(a0), __expf(a1));
    rec1[p] = make_int2(s, *(int*)&hx);
}

// ---------- gather: 1 wave/node; 8B rec (stride in int2 units); ssum in-wave; optional BN ----------
__global__ __launch_bounds__(256) void k_gather(const int* __restrict__ rowptr, const int2* __restrict__ rec,
                                                int stride,
                                                const unsigned int* __restrict__ xl32,
                                                const float* __restrict__ bias, const float* __restrict__ hprev,
                                                const float* __restrict__ scsh, int use_bn,
                                                float* __restrict__ hnew) {
    int t = threadIdx.x;
    int w = t >> 6, lane = t & 63;
    int n = blockIdx.x * 4 + w;
    if (n >= NN) return;
    int r0 = rowptr[n], r1 = rowptr[n + 1];
    float acc0 = 0.f, acc1 = 0.f, ss = 0.f;
    const unsigned int* xlp = xl32 + lane;
#pragma unroll 8
    for (int p = r0; p < r1; ++p) {
        int2 r = rec[(size_t)p * stride];        // 8B wave-uniform sequential load
        __half2 hx = *(__half2*)&r.y;
        float2 e2 = __half22float2(hx);
        float ex = (lane < 32) ? e2.x : e2.y;
        unsigned int pr = xlp[(size_t)r.x * 64]; // coalesced 256B/wave gather
        ss += ex;
        acc0 += ex * bf2f((unsigned short)(pr & 0xFFFFu));
        acc1 += ex * bf2f((unsigned short)(pr >> 16));
    }
    float inv_s = 1.f / (ss + 1e-16f);
    acc0 *= inv_s; acc1 *= inv_s;
    float o0 = 0.5f * (acc0 + __shfl_xor(acc0, 32));
    float o1 = 0.5f * (acc1 + __shfl_xor(acc1, 32));
    if (lane < 32) {
        float2 hv = ((const float2*)(hprev + (size_t)n * 64))[lane];
        if (use_bn) {
            float2 sc = ((const float2*)scsh)[lane];
            float2 sf = ((const float2*)(scsh + 64))[lane];
            hv.x = fmaxf(hv.x * sc.x + sf.x, 0.f);
            hv.y = fmaxf(hv.y * sc.y + sf.y, 0.f);
        }
        float2 bv = ((const float2*)bias)[lane];
        float2 o;
        o.x = o0 + bv.x + hv.x;
        o.y = o1 + bv.y + hv.y;
        ((float2*)(hnew + (size_t)n * 64))[lane] = o;
    }
}

// ---------- BN stats on pre-BN hbuf ----------
__global__ __launch_bounds__(256) void k_bnstat(const float* __restrict__ hbuf,
                                                float* __restrict__ part, float* __restrict__ partsq) {
    __shared__ float sA[256], sB[256];
    int t = threadIdx.x;
    int c = t & 63, r = t >> 6;
    int n0 = blockIdx.x * 80;
    float s = 0.f, s2 = 0.f;
    for (int i = 0; i < 20; ++i) {
        float v = hbuf[(size_t)(n0 + i * 4 + r) * 64 + c];
        s += v; s2 += v * v;
    }
    sA[t] = s; sB[t] = s2;
    __syncthreads();
    if (t < 64) {
        part[blockIdx.x * 64 + t]   = sA[t] + sA[t + 64] + sA[t + 128] + sA[t + 192];
        partsq[blockIdx.x * 64 + t] = sB[t] + sB[t + 64] + sB[t + 128] + sB[t + 192];
    }
}

__global__ __launch_bounds__(256) void k_bnred(const float* __restrict__ part, const float* __restrict__ partsq,
                                               const float* __restrict__ gamma, const float* __restrict__ beta,
                                               float* __restrict__ scsh) {
    __shared__ float sA[256], sB[256];
    int t = threadIdx.x;
    int c = t & 63, q = t >> 6;
    float s = 0.f, s2 = 0.f;
    for (int j = q; j < 250; j += 4) { s += part[j * 64 + c]; s2 += partsq[j * 64 + c]; }
    sA[t] = s; sB[t] = s2;
    __syncthreads();
    if (t < 64) {
        float su = sA[t] + sA[t + 64] + sA[t + 128] + sA[t + 192];
        float sq = sB[t] + sB[t + 64] + sB[t + 128] + sB[t + 192];
        float mu = su * (1.f / NN);
        float var = sq * (1.f / NN) - mu * mu;
        float sc = gamma[t] * rsqrtf(var + BN_EPS);
        scsh[t] = sc;
        scsh[64 + t] = beta[t] - mu * sc;
    }
}

extern "C" void kernel_launch(void* const* d_in, const int* in_sizes, int n_in,
                              void* d_out, int out_size, void* d_ws, size_t ws_size,
                              hipStream_t stream) {
    (void)in_sizes; (void)n_in; (void)out_size; (void)ws_size;
    const float* x     = (const float*)d_in[0];
    const int*   eidx  = (const int*)d_in[1];
    const float* eattr = (const float*)d_in[2];
    const float* instr = (const float*)d_in[3];
    const int*   batch = (const int*)d_in[4];
    const float* W_l   = (const float*)d_in[5];
    const float* W_e   = (const float*)d_in[6];
    const float* att_l = (const float*)d_in[7];
    const float* att_r = (const float*)d_in[8];
    const float* att_e = (const float*)d_in[9];
    const float* bias  = (const float*)d_in[10];
    const float* bn_g  = (const float*)d_in[11];
    const float* bn_b  = (const float*)d_in[12];
    float* out = (float*)d_out;

    const int* src = eidx;
    const int* dst = eidx + NE;

    char* ws = (char*)d_ws;
    int4*   einfo   = (int4*)ws;       ws += (size_t)NE * 16;
    int2*   rec1    = (int2*)ws;       ws += (size_t)NE * 8;
    unsigned short* xlh = (unsigned short*)ws; ws += (size_t)NN * 128 * 2;
    int*    deg     = (int*)ws;        ws += NN * 4;
    int*    rowptr  = (int*)ws;        ws += (NN + 1) * 4 + 4;
    int*    cursor  = (int*)ws;        ws += NN * 4;
    int*    bsum    = (int*)ws;        ws += 80 * 4;
    int*    boff    = (int*)ws;        ws += 80 * 4;
    float*  alc     = (float*)ws;      ws += NN * 2 * 4;
    float*  ar      = (float*)ws;      ws += NN * 2 * 4;
    float*  insl01  = (float*)ws;      ws += 2 * 128 * 128 * 4;
    float*  ve01    = (float*)ws;      ws += 256 * 4;
    float*  w2e01   = (float*)ws;      ws += 256 * 4;
    float*  ce01    = (float*)ws;      ws += 2 * 256 * 4;
    float*  hbuf    = (float*)ws;      ws += (size_t)NN * 64 * 4;
    float*  part    = (float*)ws;      ws += 250 * 64 * 4;
    float*  partsq  = (float*)ws;      ws += 250 * 64 * 4;
    float*  scsh    = (float*)ws;      ws += 128 * 4;

    hipMemsetAsync(deg, 0, NN * 4, stream);
    k_hist<<<(NE + 255) / 256, 256, 0, stream>>>(dst, deg);
    k_scanA<<<NBLK, 256, 0, stream>>>(deg, bsum);
    k_scanB<<<1, 64, 0, stream>>>(bsum, boff, rowptr);
    k_scanC<<<NBLK, 256, 0, stream>>>(deg, boff, rowptr, cursor);

    k_p1<<<2, 256, 0, stream>>>(W_e, att_e, ve01, w2e01);
    k_p2both<<<130, 256, 0, stream>>>(instr, W_l, w2e01, insl01, ce01);

    // layer 0: node linear, then fused edge dots (both layers) + L0 logits, CSR order
    k_node<<<(NN + 7) / 8, 256, 0, stream>>>(x, W_l, insl01, batch,
                                             att_l, att_r, (const float2*)ce01,
                                             scsh, 0, xlh, alc, ar);
    k_sced<<<NE / 64, 64, 0, stream>>>(src, dst, eattr, ve01,
                                       (const float2*)alc, (const float2*)ar, cursor, einfo);
    k_gather<<<NN / 4, 256, 0, stream>>>(rowptr, (const int2*)einfo + 1, 2,
                                         (const unsigned int*)xlh,
                                         bias, x, scsh, 0, hbuf);
    k_bnstat<<<250, 256, 0, stream>>>(hbuf, part, partsq);
    k_bnred<<<1, 256, 0, stream>>>(part, partsq, bn_g, bn_b, scsh);

    // layer 1
    k_node<<<(NN + 7) / 8, 256, 0, stream>>>(hbuf, W_l + 128 * 128, insl01 + 16384, batch,
                                             att_l + 128, att_r + 128, (const float2*)(ce01 + 256),
                                             scsh, 1, xlh, alc, ar);
    k_attnexp<<<(NE + 255) / 256, 256, 0, stream>>>(einfo, (const float2*)alc, (const float2*)ar, rec1);
    k_gather<<<NN / 4, 256, 0, stream>>>(rowptr, rec1, 1, (const unsigned int*)xlh,
                                         bias + 64, hbuf, scsh, 1, out);
}